// Round 22
// baseline (342.023 us; speedup 1.0000x reference)
//
#include <hip/hip_runtime.h>
#include <hip/hip_bf16.h>
#include <cstdint>

typedef unsigned short u16;
typedef __attribute__((ext_vector_type(8))) short bh8;   // 8 bf16 (4 VGPR)
typedef __attribute__((ext_vector_type(4))) short sh4;   // 4 bf16
typedef __attribute__((ext_vector_type(4))) float fx4;

#define NTOK 2048
#define HDIM 1024
#define NE 8
#define FDIM 2048

#define VMCNT(n) asm volatile("s_waitcnt vmcnt(" #n ")" ::: "memory")
#define LGKM0()  asm volatile("s_waitcnt lgkmcnt(0)" ::: "memory")
#define SBAR()   __builtin_amdgcn_s_barrier()
#define SCB()    __builtin_amdgcn_sched_barrier(0)

__device__ __forceinline__ u16 f2bf(float f) {
    __hip_bfloat16 h = __float2bfloat16(f);
    return __builtin_bit_cast(u16, h);
}

// async global->LDS, 16B per lane. LDS dest is wave-uniform base (+lane*16 implicit).
__device__ __forceinline__ void gll16(const void* g, void* l) {
    __builtin_amdgcn_global_load_lds(
        (const __attribute__((address_space(1))) void*)g,
        (__attribute__((address_space(3))) void*)l, 16, 0, 0);
}

// ---------------- arena layout (groups of 8 elements): wq|wk|wv|wo|w1|w2|w3
#define N8_WQ 131072
#define N8_WK 32768
#define N8_WV 32768
#define N8_WO 131072
#define N8_W  2097152
#define B0q 0
#define B1k (B0q + N8_WQ)
#define B2v (B1k + N8_WK)
#define B3o (B2v + N8_WV)
#define B4a (B3o + N8_WO)          // qkvo total = 327680
#define B5b (B4a + N8_W)
#define B6c (B5b + N8_W)
#define N8TOT (B6c + N8_W)
#define N8QKVO B4a
#define N8_W13 (2 * N8_W)

// nontemporal f32x8 -> bf16x8 convert (streaming; avoids L2/L3 pollution)
__device__ __forceinline__ void conv8_nt(const float* __restrict__ src, size_t li,
                                         u16* __restrict__ dst, size_t di) {
    const fx4 a = __builtin_nontemporal_load((const fx4*)&src[li]);
    const fx4 b = __builtin_nontemporal_load((const fx4*)&src[li + 4]);
    bh8 o;
    #pragma unroll
    for (int j = 0; j < 4; ++j) {
        o[j]     = (short)f2bf(a[j]);
        o[j + 4] = (short)f2bf(b[j]);
    }
    __builtin_nontemporal_store(o, (bh8*)&dst[di]);
}

__device__ __forceinline__ void conv8(const float* __restrict__ src, size_t li,
                                      u16* __restrict__ dst, size_t di) {
    const fx4 a = *(const fx4*)&src[li];
    const fx4 b = *(const fx4*)&src[li + 4];
    bh8 o;
    #pragma unroll
    for (int j = 0; j < 4; ++j) {
        o[j]     = (short)f2bf(a[j]);
        o[j + 4] = (short)f2bf(b[j]);
    }
    *(bh8*)&dst[di] = o;
}

// ---------------- fused prologue: qkvo convert + rope table + rmsnorm1
// grid 2560 blocks: [0,256) convert qkvo; [256,512) rope; [512,2560) rmsnorm.
__global__ __launch_bounds__(256)
void prologue_k(const float* __restrict__ wq, const float* __restrict__ wk,
                const float* __restrict__ wv, const float* __restrict__ wo,
                u16* __restrict__ arena,
                float* __restrict__ cosT, float* __restrict__ sinT,
                const float* __restrict__ X, const float* __restrict__ W,
                u16* __restrict__ O) {
    const int bid = blockIdx.x;
    const int tid = threadIdx.x;
    if (bid < 256) {
        int i = bid * 256 + tid;
        const int stride = 256 * 256;
        for (; i < N8QKVO; i += stride) {
            const float* src;
            int base;
            if (i < B1k)      { src = wq; base = B0q; }
            else if (i < B2v) { src = wk; base = B1k; }
            else if (i < B3o) { src = wv; base = B2v; }
            else              { src = wo; base = B3o; }
            conv8(src, (size_t)(i - base) * 8, arena, (size_t)i * 8);
        }
        return;
    }
    if (bid < 512) {
        const int idx = (bid - 256) * 256 + tid;      // 2048*32
        const int t = idx >> 5, i = idx & 31;
        const float freq = powf(10000.0f, -(float)i * (1.0f / 32.0f));
        const float ang = (float)t * freq;
        float s, c;
        sincosf(ang, &s, &c);
        cosT[idx] = c;
        sinT[idx] = s;
        return;
    }
    // rmsnorm 1
    const int t = bid - 512;
    const fx4 v = *(const fx4*)&X[(size_t)t * HDIM + tid * 4];
    float ss = v[0]*v[0] + v[1]*v[1] + v[2]*v[2] + v[3]*v[3];
    #pragma unroll
    for (int o = 1; o < 64; o <<= 1) ss += __shfl_xor(ss, o);
    __shared__ float red[4];
    if ((tid & 63) == 0) red[tid >> 6] = ss;
    __syncthreads();
    const float inv = rsqrtf((red[0] + red[1] + red[2] + red[3]) * (1.0f / HDIM) + 1e-5f);
    const fx4 w = *(const fx4*)&W[tid * 4];
    sh4 o4;
    #pragma unroll
    for (int i = 0; i < 4; ++i) o4[i] = (short)f2bf(v[i] * inv * w[i]);
    *(sh4*)&O[(size_t)t * HDIM + tid * 4] = o4;
}

// -------------------------------------------- rmsnorm 2 + router logits (f32)
__global__ __launch_bounds__(256)
void rmsnorm2_router_k(const float* __restrict__ X, const float* __restrict__ W,
                       const float* __restrict__ GW, u16* __restrict__ O,
                       float* __restrict__ LOGI) {
    const int t = blockIdx.x;
    const int tid = threadIdx.x;
    const fx4 v = *(const fx4*)&X[(size_t)t * HDIM + tid * 4];
    float ss = v[0]*v[0] + v[1]*v[1] + v[2]*v[2] + v[3]*v[3];
    #pragma unroll
    for (int o = 1; o < 64; o <<= 1) ss += __shfl_xor(ss, o);
    __shared__ float red[4];
    if ((tid & 63) == 0) red[tid >> 6] = ss;
    __syncthreads();
    const float inv = rsqrtf((red[0] + red[1] + red[2] + red[3]) * (1.0f / HDIM) + 1e-5f);
    const fx4 w = *(const fx4*)&W[tid * 4];
    fx4 xn;
    #pragma unroll
    for (int i = 0; i < 4; ++i) xn[i] = v[i] * inv * w[i];
    sh4 o4;
    #pragma unroll
    for (int i = 0; i < 4; ++i) o4[i] = (short)f2bf(xn[i]);
    *(sh4*)&O[(size_t)t * HDIM + tid * 4] = o4;

    float part[NE];
    #pragma unroll
    for (int e = 0; e < NE; ++e) {
        const fx4 g = *(const fx4*)&GW[(size_t)e * HDIM + tid * 4];
        part[e] = g[0]*xn[0] + g[1]*xn[1] + g[2]*xn[2] + g[3]*xn[3];
    }
    #pragma unroll
    for (int e = 0; e < NE; ++e)
        #pragma unroll
        for (int o = 1; o < 64; o <<= 1) part[e] += __shfl_xor(part[e], o);
    __shared__ float red8[4][NE];
    if ((tid & 63) == 0) {
        #pragma unroll
        for (int e = 0; e < NE; ++e) red8[tid >> 6][e] = part[e];
    }
    __syncthreads();
    if (tid < NE)
        LOGI[(size_t)t * NE + tid] = red8[0][tid] + red8[1][tid] + red8[2][tid] + red8[3][tid];
}

// ---------------------------------------------------------------- router top2
__global__ __launch_bounds__(256)
void router_topk_k(const float* __restrict__ LOGI, int* __restrict__ counts,
                   int* __restrict__ tokslot, float* __restrict__ wtb) {
    const int t = blockIdx.x * 256 + threadIdx.x;
    float l[NE];
    #pragma unroll
    for (int e = 0; e < NE; ++e) l[e] = LOGI[(size_t)t * NE + e];
    int i0 = 0;
    #pragma unroll
    for (int e = 1; e < NE; ++e) if (l[e] > l[i0]) i0 = e;
    int i1 = (i0 == 0) ? 1 : 0;
    #pragma unroll
    for (int e = 0; e < NE; ++e) if (e != i0 && l[e] > l[i1]) i1 = e;
    float e1 = __expf(l[i1] - l[i0]);
    float w0 = 1.0f / (1.0f + e1);
    float w1 = 1.0f - w0;
    int p0 = atomicAdd(&counts[i0], 1);
    tokslot[i0 * NTOK + p0] = t * 2;
    wtb[i0 * NTOK + p0] = w0;
    int p1 = atomicAdd(&counts[i1], 1);
    tokslot[i1 * NTOK + p1] = t * 2 + 1;
    wtb[i1 * NTOK + p1] = w1;
}

// --------------------------------------------- fused QKV GEMM (one launch)
// B = arena rows 0..1535 (wq|wk|wv stacked, K=1024). 64x64 tile, 4-buf
// 3-lookahead pipeline. n-tile epilogue: [0,16) Q+RoPE -> qb; [16,20) K+RoPE
// -> kb; [20,24) V transposed -> vbt. grid (24, 32).
__global__ __launch_bounds__(256)
void qkv_gemm_k(const u16* __restrict__ A, const u16* __restrict__ Bw,
                u16* __restrict__ Qb, u16* __restrict__ Kb, u16* __restrict__ VTb,
                const float* __restrict__ cosT, const float* __restrict__ sinT) {
    __shared__ u16 As[4][64 * 32];
    __shared__ u16 Bs[4][64 * 32];

    const int tid = threadIdx.x;
    const int lane = tid & 63;
    const int wid = tid >> 6;
    const int lrow = lane & 15, lgrp = lane >> 4;
    const int wm = wid * 16;
    const int soff = (lgrp ^ ((lrow >> 1) & 3)) * 8;

    const int m0 = blockIdx.y * 64;
    const int nt = blockIdx.x;
    const int n0 = nt * 64;                 // global arena row base

    const int gseg = ((tid & 3) ^ ((tid >> 3) & 3)) * 8;
    const u16* apg = A + (size_t)(m0 + (tid >> 2)) * 1024 + gseg;
    const u16* bpg = Bw + (size_t)(n0 + (tid >> 2)) * 1024 + gseg;

    fx4 acc[4];
    #pragma unroll
    for (int i = 0; i < 4; ++i) acc[i] = fx4{0.f, 0.f, 0.f, 0.f};

#define G_STG(BUF, KK) gll16(apg + (KK), &As[BUF][wid * 512]); \
                       gll16(bpg + (KK), &Bs[BUF][wid * 512]);
#define G_CMP(BUF)                                                             \
    {                                                                          \
        const bh8 af = *(const bh8*)&As[BUF][(wm + lrow) * 32 + soff];         \
        _Pragma("unroll")                                                      \
        for (int ni = 0; ni < 4; ++ni) {                                       \
            const bh8 bf = *(const bh8*)&Bs[BUF][(ni * 16 + lrow) * 32 + soff];\
            acc[ni] = __builtin_amdgcn_mfma_f32_16x16x32_bf16(af, bf, acc[ni], 0, 0, 0); \
        }                                                                      \
    }
#define G_PHASE(BUF_ST, KOFF, BUF_CM)                                          \
    { const int kn = (k0 + (KOFF) < 1024) ? k0 + (KOFF) : 0; G_STG(BUF_ST, kn) } \
    VMCNT(6); SBAR(); SCB();                                                   \
    G_CMP(BUF_CM)                                                              \
    LGKM0(); SBAR();

    G_STG(0, 0) G_STG(1, 32) G_STG(2, 64)
    for (int k0 = 0; k0 < 1024; k0 += 128) {
        G_PHASE(3, 96, 0)
        G_PHASE(0, 128, 1)
        G_PHASE(1, 160, 2)
        G_PHASE(2, 192, 3)
    }
    VMCNT(0);
#undef G_STG
#undef G_CMP
#undef G_PHASE

    if (nt < 20) {
        // Q (nt<16) or K (16<=nt<20): RoPE epilogue; each 64-col tile = one head
        u16* dst = (nt < 16) ? Qb : Kb;
        const int N = (nt < 16) ? 1024 : 256;
        const int cb = (nt < 16) ? n0 : (nt - 16) * 64;
        #pragma unroll
        for (int j = 0; j < 4; ++j) {
            const int r = m0 + wm + lgrp * 4 + j;
            #pragma unroll
            for (int ni = 0; ni < 2; ++ni) {
                const int d = ni * 16 + lrow;            // d < 32
                const float cv = cosT[r * 32 + d];
                const float sv = sinT[r * 32 + d];
                const float v0 = acc[ni][j];
                const float v1 = acc[ni + 2][j];
                dst[(size_t)r * N + cb + d]      = f2bf(v0 * cv - v1 * sv);
                dst[(size_t)r * N + cb + d + 32] = f2bf(v1 * cv + v0 * sv);
            }
        }
    } else {
        // V: transposed bf16 write; VTb is [256][NTOK]
        #pragma unroll
        for (int ni = 0; ni < 4; ++ni) {
            const int c = (nt - 20) * 64 + ni * 16 + lrow;
            const int r = m0 + wm + lgrp * 4;
            sh4 o4;
            #pragma unroll
            for (int j = 0; j < 4; ++j) o4[j] = (short)f2bf(acc[ni][j]);
            *(sh4*)&VTb[(size_t)c * NTOK + r] = o4;
        }
    }
}

// ---------------------------- O-projection GEMM + residual + fused w2 convert
// z == 0: 64x64 tile GEMM (grid 16x32), C = ctx @ wo^T + residual (f32).
// z == 1: 512 grid-stride blocks convert w2 f32 -> bf16 (nontemporal, 4x MLP).
__global__ __launch_bounds__(256)
void o_gemm_conv_k(const u16* __restrict__ A, const u16* __restrict__ B,
                   float* __restrict__ Cf, const float* __restrict__ res,
                   const float* __restrict__ w2, u16* __restrict__ w2b) {
    if (blockIdx.z == 1) {
        const int bid = blockIdx.y * 16 + blockIdx.x;      // 0..511
        const int stride = 512 * 256;
        int i = bid * 256 + threadIdx.x;
        // N8_W / stride = 16 iterations; unroll 4
        #pragma unroll 1
        for (int k = 0; k < 4; ++k) {
            #pragma unroll
            for (int u = 0; u < 4; ++u)
                conv8_nt(w2, (size_t)(i + u * stride) * 8, w2b, (size_t)(i + u * stride) * 8);
            i += 4 * stride;
        }
        return;
    }

    __shared__ u16 As[4][64 * 32];
    __shared__ u16 Bs[4][64 * 32];

    const int tid = threadIdx.x;
    const int lane = tid & 63;
    const int wid = tid >> 6;
    const int lrow = lane & 15, lgrp = lane >> 4;
    const int wm = wid * 16;
    const int soff = (lgrp ^ ((lrow >> 1) & 3)) * 8;

    const int m0 = blockIdx.y * 64;
    const int n0 = blockIdx.x * 64;

    const int gseg = ((tid & 3) ^ ((tid >> 3) & 3)) * 8;
    const u16* apg = A + (size_t)(m0 + (tid >> 2)) * 1024 + gseg;
    const u16* bpg = B + (size_t)(n0 + (tid >> 2)) * 1024 + gseg;

    fx4 acc[4];
    #pragma unroll
    for (int i = 0; i < 4; ++i) acc[i] = fx4{0.f, 0.f, 0.f, 0.f};

#define G_STG(BUF, KK) gll16(apg + (KK), &As[BUF][wid * 512]); \
                       gll16(bpg + (KK), &Bs[BUF][wid * 512]);
#define G_CMP(BUF)                                                             \
    {                                                                          \
        const bh8 af = *(const bh8*)&As[BUF][(wm + lrow) * 32 + soff];         \
        _Pragma("unroll")                                                      \
        for (int ni = 0; ni < 4; ++ni) {                                       \
            const bh8 bf = *(const bh8*)&Bs[BUF][(ni * 16 + lrow) * 32 + soff];\
            acc[ni] = __builtin_amdgcn_mfma_f32_16x16x32_bf16(af, bf, acc[ni], 0, 0, 0); \
        }                                                                      \
    }
#define G_PHASE(BUF_ST, KOFF, BUF_CM)                                          \
    { const int kn = (k0 + (KOFF) < 1024) ? k0 + (KOFF) : 0; G_STG(BUF_ST, kn) } \
    VMCNT(6); SBAR(); SCB();                                                   \
    G_CMP(BUF_CM)                                                              \
    LGKM0(); SBAR();

    G_STG(0, 0) G_STG(1, 32) G_STG(2, 64)
    for (int k0 = 0; k0 < 1024; k0 += 128) {
        G_PHASE(3, 96, 0)
        G_PHASE(0, 128, 1)
        G_PHASE(1, 160, 2)
        G_PHASE(2, 192, 3)
    }
    VMCNT(0);
#undef G_STG
#undef G_CMP
#undef G_PHASE

    #pragma unroll
    for (int j = 0; j < 4; ++j) {
        const int r = m0 + wm + lgrp * 4 + j;
        #pragma unroll
        for (int ni = 0; ni < 4; ++ni) {
            const int c = n0 + ni * 16 + lrow;
            Cf[(size_t)r * 1024 + c] = acc[ni][j] + res[(size_t)r * 1024 + c];
        }
    }
}

// --------------------------- flash attention (split-KV) + fused w1|w3 convert
// z in [0,4): attention chunks (fixed-max softmax, shift-exact; V pre-
// transposed). z in {4,5}: 1024 grid-stride blocks convert w1|w3 (NT, 4x MLP).
__global__ __launch_bounds__(256)
void attn_conv_k(const u16* __restrict__ Q, const u16* __restrict__ Kg,
                 const u16* __restrict__ VTg, float* __restrict__ pacc,
                 float* __restrict__ pl,
                 const float* __restrict__ w1, const float* __restrict__ w3,
                 u16* __restrict__ arena_moe) {
    if (blockIdx.z >= 4) {
        const int bid = (blockIdx.z - 4) * 512 + blockIdx.y * 32 + blockIdx.x; // 0..1023
        const int stride = 1024 * 256;
        int i = bid * 256 + threadIdx.x;
        // N8_W13 / stride = 16 iterations; unroll 4 for MLP
        #pragma unroll 1
        for (int k = 0; k < 4; ++k) {
            #pragma unroll
            for (int u = 0; u < 4; ++u) {
                const int ii = i + u * stride;
                const float* s = (ii < N8_W) ? w1 : w3;
                const size_t li = (size_t)(ii < N8_W ? ii : ii - N8_W) * 8;
                const size_t di = (size_t)(ii < N8_W ? ii : ii + N8_W) * 8;  // w3 -> rel 2*N8_W
                conv8_nt(s, li, arena_moe, di);
            }
            i += 4 * stride;
        }
        return;
    }

    const int qt = blockIdx.x;
    const int h = blockIdx.y;
    const int c = blockIdx.z;
    if (c * 8 > qt) return;
    const int t0 = c * 8;
    const int tend = min(qt + 1, t0 + 8);
    const int kvh = h >> 2;

    const int tid = threadIdx.x;
    const int lane = tid & 63;
    const int wid = tid >> 6;
    const int lrow = lane & 15, lgrp = lane >> 4;

    __shared__ u16 Ks[64 * 66];
    __shared__ u16 Vs[64 * 66];
    __shared__ u16 Ps[4][16 * 66];

    const int qbase = qt * 64 + wid * 16;

    bh8 qf[2];
    #pragma unroll
    for (int kf = 0; kf < 2; ++kf)
        qf[kf] = *(const bh8*)&Q[(size_t)(qbase + lrow) * 1024 + h * 64 + kf * 32 + lgrp * 8];

    fx4 acc[4];
    #pragma unroll
    for (int ni = 0; ni < 4; ++ni) acc[ni] = fx4{0.f, 0.f, 0.f, 0.f};
    float lsum[4];
    #pragma unroll
    for (int j = 0; j < 4; ++j) lsum[j] = 0.f;

    const int srow = tid >> 2;
    const int sseg = (tid & 3) * 16;

    size_t gk = (size_t)(t0 * 64 + srow) * 256 + kvh * 64 + sseg;
    size_t gv = (size_t)(kvh * 64 + srow) * NTOK + t0 * 64 + sseg;
    bh8 kva = *(const bh8*)&Kg[gk];
    bh8 kvb = *(const bh8*)&Kg[gk + 8];
    bh8 vva = *(const bh8*)&VTg[gv];
    bh8 vvb = *(const bh8*)&VTg[gv + 8];

    for (int it = t0; it < tend; ++it) {
        const int kv0 = it * 64;
        __syncthreads();
        *(bh8*)&Ks[srow * 66 + sseg]     = kva;
        *(bh8*)&Ks[srow * 66 + sseg + 8] = kvb;
        *(bh8*)&Vs[srow * 66 + sseg]     = vva;
        *(bh8*)&Vs[srow * 66 + sseg + 8] = vvb;
        __syncthreads();

        const int itn = (it + 1 < tend) ? it + 1 : it;
        const size_t gk2 = (size_t)(itn * 64 + srow) * 256 + kvh * 64 + sseg;
        const size_t gv2 = (size_t)(kvh * 64 + srow) * NTOK + itn * 64 + sseg;
        kva = *(const bh8*)&Kg[gk2];
        kvb = *(const bh8*)&Kg[gk2 + 8];
        vva = *(const bh8*)&VTg[gv2];
        vvb = *(const bh8*)&VTg[gv2 + 8];

        fx4 s[4];
        #pragma unroll
        for (int nf = 0; nf < 4; ++nf) s[nf] = fx4{0.f, 0.f, 0.f, 0.f};
        #pragma unroll
        for (int kf = 0; kf < 2; ++kf) {
            #pragma unroll
            for (int nf = 0; nf < 4; ++nf) {
                const bh8 kfr = *(const bh8*)&Ks[(nf * 16 + lrow) * 66 + kf * 32 + lgrp * 8];
                s[nf] = __builtin_amdgcn_mfma_f32_16x16x32_bf16(qf[kf], kfr, s[nf], 0, 0, 0);
            }
        }

        #pragma unroll
        for (int nf = 0; nf < 4; ++nf)
            #pragma unroll
            for (int j = 0; j < 4; ++j) {
                const int qr = qbase + lgrp * 4 + j;
                const int kp = kv0 + nf * 16 + lrow;
                float p = __expf(fmaf(s[nf][j], 0.125f, -24.0f));
                p = (kp > qr) ? 0.f : p;
                s[nf][j] = p;
                lsum[j] += p;
            }

        u16* pw = Ps[wid];
        #pragma unroll
        for (int nf = 0; nf < 4; ++nf)
            #pragma unroll
            for (int j = 0; j < 4; ++j)
                pw[(lgrp * 4 + j) * 66 + nf * 16 + lrow] = f2bf(s[nf][j]);

        #pragma unroll
        for (int kf = 0; kf < 2; ++kf) {
            const bh8 pa = *(const bh8*)&pw[lrow * 66 + kf * 32 + lgrp * 8];
            #pragma unroll
            for (int ni = 0; ni < 4; ++ni) {
                const bh8 vb = *(const bh8*)&Vs[(ni * 16 + lrow) * 66 + kf * 32 + lgrp * 8];
                acc[ni] = __builtin_amdgcn_mfma_f32_16x16x32_bf16(pa, vb, acc[ni], 0, 0, 0);
            }
        }
    }

    #pragma unroll
    for (int j = 0; j < 4; ++j) {
        float l = lsum[j];
        #pragma unroll
        for (int o = 1; o < 16; o <<= 1) l += __shfl_xor(l, o);
        lsum[j] = l;
    }

    #pragma unroll
    for (int j = 0; j < 4; ++j) {
        const int r = qbase + lgrp * 4 + j;
        const size_t base = ((size_t)(h * NTOK + r) * 4 + c) * 64;
        #pragma unroll
        for (int ni = 0; ni < 4; ++ni)
            pacc[base + ni * 16 + lrow] = acc[ni][j];
        if (lrow == 0)
            pl[(size_t)(h * NTOK + r) * 4 + c] = lsum[j];
    }
}

// --------------------------------------------- attention combine (plain sums)
__global__ __launch_bounds__(256)
void attn_combine_k(const float* __restrict__ pacc, const float* __restrict__ pl,
                    u16* __restrict__ O) {
    const int idx = blockIdx.x * 4 + (threadIdx.x >> 6);
    const int d = threadIdx.x & 63;
    const int h = idx >> 11;
    const int qrow = idx & 2047;
    const int nch = (qrow >> 9) + 1;

    float den = 0.f, num = 0.f;
    for (int c = 0; c < nch; ++c) {
        den += pl[(size_t)idx * 4 + c];
        num += pacc[((size_t)idx * 4 + c) * 64 + d];
    }
    O[(size_t)qrow * 1024 + h * 64 + d] = f2bf(num / den);
}

// ------------------------------------------------- MoE up (w1,w3 + SiLU*mul)
// 64x128 tile, 4 waves (2x2). 4-buffer 3-phase-lookahead:
// stage(t+3), vmcnt(15), compute(t). 80KB LDS. grid (16, 32, NE).
__global__ __launch_bounds__(256)
void moe_up_k(const u16* __restrict__ X, const u16* __restrict__ W1b,
              const u16* __restrict__ W3b, const int* __restrict__ counts,
              const int* __restrict__ tokslot, u16* __restrict__ G) {
    const int e = blockIdx.z;
    const int cnt = counts[e];
    const int m0 = blockIdx.y * 64;
    if (m0 >= cnt) return;
    const int n0 = blockIdx.x * 128;

    __shared__ u16 As[4][64 * 32];
    __shared__ u16 B1s[4][128 * 32];
    __shared__ u16 B3s[4][128 * 32];

    const int tid = threadIdx.x;
    const int lane = tid & 63, wid = tid >> 6;
    const int wm = (wid >> 1) * 32, wn = (wid & 1) * 64;
    const int lrow = lane & 15, lgrp = lane >> 4;
    const int soff = (lgrp ^ ((lrow >> 1) & 3)) * 8;

    const int gseg = ((tid & 3) ^ ((tid >> 3) & 3)) * 8;
    const int arow = m0 + (tid >> 2);
    const int tok = (arow < cnt) ? (tokslot[e * NTOK + arow] >> 1) : 0;
    const u16* apg = X + (size_t)tok * HDIM + gseg;
    const size_t eoff = (size_t)e * FDIM * HDIM;
    const u16* b1pg = W1b + eoff + (size_t)(n0 + (tid >> 2)) * HDIM + gseg;
    const u16* b3pg = W3b + eoff + (size_t)(n0 + (tid >> 2)) * HDIM + gseg;
    const size_t rr = (size_t)64 * HDIM;

    fx4 acc1[2][4], acc3[2][4];
    #pragma unroll
    for (int i = 0; i < 2; ++i)
        #pragma unroll
        for (int j = 0; j < 4; ++j) {
            acc1[i][j] = fx4{0.f, 0.f, 0.f, 0.f};
            acc3[i][j] = fx4{0.f, 0.f, 0.f, 0.f};
        }

#define U_STG(BUF, KK)                                          \
    gll16(apg + (KK), &As[BUF][wid * 512]);                     \
    gll16(b1pg + (KK), &B1s[BUF][wid * 512]);                   \
    gll16(b1pg + rr + (KK), &B1s[BUF][2048 + wid * 512]);       \
    gll16(b3pg + (KK), &B3s[BUF][wid * 512]);                   \
    gll16(b3pg + rr + (KK), &B3s[BUF][2048 + wid * 512]);

#define U_CMP(BUF)                                                                   \
    {                                                                                \
        bh8 af[2], b1f[4], b3f[4];                                                   \
        _Pragma("unroll")                                                            \
        for (int mi = 0; mi < 2; ++mi)                                               \
            af[mi] = *(const bh8*)&As[BUF][(wm + mi * 16 + lrow) * 32 + soff];       \
        _Pragma("unroll")                                                            \
        for (int ni = 0; ni < 4; ++ni) {                                             \
            b1f[ni] = *(const bh8*)&B1s[BUF][(wn + ni * 16 + lrow) * 32 + soff];     \
            b3f[ni] = *(const bh8*)&B3s[BUF][(wn + ni * 16 + lrow) * 32 + soff];     \
        }                                                                            \
        _Pragma("unroll")                                                            \
        for (int mi = 0; mi < 2; ++mi)                                               \
            _Pragma("unroll")                                                        \
            for (int ni = 0; ni < 4; ++ni) {                                         \
                acc1[mi][ni] = __builtin_amdgcn_mfma_f32_16x16x32_bf16(af[mi], b1f[ni], acc1[mi][ni], 0, 0, 0); \
                acc3[mi][ni] = __builtin_amdgcn_mfma_f32_16x16x32_bf16(af[mi], b3f[ni], acc3[mi][ni], 0, 0, 0); \
            }                                                                        \
    }

#define U_PHASE(BUF_ST, KOFF, BUF_CM)                                          \
    { const int kn = (k0 + (KOFF) < HDIM) ? k0 + (KOFF) : 0; U_STG(BUF_ST, kn) } \
    VMCNT(15); SBAR(); SCB();                                                  \
    U_CMP(BUF_CM)                                                              \
    LGKM0(); SBAR();

    U_STG(0, 0) U_STG(1, 32) U_STG(2, 64)
    for (int k0 = 0; k0 < HDIM; k0 += 128) {
        U_PHASE(3, 96, 0)
        U_PHASE(0, 128, 1)
        U_PHASE(1, 160, 2)
        U_PHASE(2, 192, 3)
    }
    VMCNT(0);
#undef U_STG
#undef U_CMP
#undef U_PHASE

    #pragma unroll
    for (int mi = 0; mi < 2; ++mi)
        #pragma unroll
        for (int j = 0; j < 4; ++j) {
            const int r = m0 + wm + mi * 16 + lgrp * 4 + j;
            if (r < cnt) {
                #pragma unroll
                for (int ni = 0; ni < 4; ++ni) {
                    const int c = n0 + wn + ni * 16 + lrow;
                    const float h1 = acc1[mi][ni][j];
                    const float h3 = acc3[mi][ni][j];
                    const float gv = h1 / (1.0f + __expf(-h1)) * h3;
                    G[((size_t)e * NTOK + r) * FDIM + c] = f2bf(gv);
                }
            }
        }
}

// -------------------------------------------------- MoE down (scaled scatter)
// 64x64 tile, K=2048, 4-buf 3-lookahead pipeline, scatter epilogue.
__global__ __launch_bounds__(256)
void moe_down_k(const u16* __restrict__ G, const u16* __restrict__ W2b,
                const int* __restrict__ counts, const int* __restrict__ tokslot,
                const float* __restrict__ wtb, float* __restrict__ MO) {
    const int e = blockIdx.z;
    const int cnt = counts[e];
    const int m0 = blockIdx.y * 64;
    if (m0 >= cnt) return;
    const int n0 = blockIdx.x * 64;

    __shared__ u16 As[4][64 * 32];
    __shared__ u16 Bs[4][64 * 32];

    const int tid = threadIdx.x;
    const int lane = tid & 63;
    const int wid = tid >> 6;
    const int lrow = lane & 15, lgrp = lane >> 4;
    const int wm = wid * 16;
    const int soff = (lgrp ^ ((lrow >> 1) & 3)) * 8;

    const int gseg = ((tid & 3) ^ ((tid >> 3) & 3)) * 8;
    const u16* apg = G + ((size_t)e * NTOK + m0 + (tid >> 2)) * FDIM + gseg;
    const u16* bpg = W2b + (size_t)e * HDIM * FDIM + (size_t)(n0 + (tid >> 2)) * FDIM + gseg;

    fx4 acc[4];
    #pragma unroll
    for (int i = 0; i < 4; ++i) acc[i] = fx4{0.f, 0.f, 0.f, 0.f};

#define D_STG(BUF, KK) gll16(apg + (KK), &As[BUF][wid * 512]); \
                       gll16(bpg + (KK), &Bs[BUF][wid * 512]);
#define D_CMP(BUF)                                                             \
    {                                                                          \
        const bh8 af = *(const bh8*)&As[BUF][(wm + lrow) * 32 + soff];         \
        _Pragma("unroll")                                                      \
        for (int ni = 0; ni < 4; ++ni) {                                       \
            const bh8 bf = *(const bh8*)&Bs[BUF][(ni * 16 + lrow) * 32 + soff];\
            acc[ni] = __builtin_amdgcn_mfma_f32_16x16x32_bf16(af, bf, acc[ni], 0, 0, 0); \
        }                                                                      \
    }
#define D_PHASE(BUF_ST, KOFF, BUF_CM)                                          \
    { const int kn = (k0 + (KOFF) < FDIM) ? k0 + (KOFF) : 0; D_STG(BUF_ST, kn) } \
    VMCNT(6); SBAR(); SCB();                                                   \
    D_CMP(BUF_CM)                                                              \
    LGKM0(); SBAR();

    D_STG(0, 0) D_STG(1, 32) D_STG(2, 64)
    for (int k0 = 0; k0 < FDIM; k0 += 128) {
        D_PHASE(3, 96, 0)
        D_PHASE(0, 128, 1)
        D_PHASE(1, 160, 2)
        D_PHASE(2, 192, 3)
    }
    VMCNT(0);
#undef D_STG
#undef D_CMP
#undef D_PHASE

    #pragma unroll
    for (int j = 0; j < 4; ++j) {
        const int r = m0 + wm + lgrp * 4 + j;
        if (r < cnt) {
            const int ts = tokslot[e * NTOK + r];
            const float wgt = wtb[e * NTOK + r];
            const int tt = ts >> 1;
            const int sl = ts & 1;
            #pragma unroll
            for (int ni = 0; ni < 4; ++ni) {
                const int c = n0 + ni * 16 + lrow;
                MO[((size_t)sl * NTOK + tt) * HDIM + c] = acc[ni][j] * wgt;
            }
        }
    }
}

// ---------------------------------------------------------------- final add
__global__ __launch_bounds__(256)
void final_add_k(const float* __restrict__ A, const float* __restrict__ B0,
                 const float* __restrict__ B1, float* __restrict__ O) {
    const size_t i = ((size_t)blockIdx.x * 256 + threadIdx.x) * 4;
    const fx4 a = *(const fx4*)&A[i];
    const fx4 b = *(const fx4*)&B0[i];
    const fx4 c = *(const fx4*)&B1[i];
    fx4 r;
    #pragma unroll
    for (int k = 0; k < 4; ++k) r[k] = a[k] + b[k] + c[k];
    *(fx4*)&O[i] = r;
}

// ---------------------------------------------------------------- launcher
extern "C" void kernel_launch(void* const* d_in, const int* in_sizes, int n_in,
                              void* d_out, int out_size, void* d_ws, size_t ws_size,
                              hipStream_t stream) {
    const float* x   = (const float*)d_in[0];
    const float* ln1 = (const float*)d_in[2];
    const float* ln2 = (const float*)d_in[3];
    const float* wq  = (const float*)d_in[4];
    const float* wk  = (const float*)d_in[5];
    const float* wv  = (const float*)d_in[6];
    const float* wo  = (const float*)d_in[7];
    const float* gw  = (const float*)d_in[8];
    const float* w1  = (const float*)d_in[9];
    const float* w2  = (const float*)d_in[10];
    const float* w3  = (const float*)d_in[11];

    float* out_h = (float*)d_out;
    float* out_logits = out_h + (size_t)NTOK * HDIM;

    uint8_t* wsb = (uint8_t*)d_ws;
    size_t off = 0;
    auto alloc = [&](size_t bytes) -> void* {
        void* ptr = wsb + off;
        off = (off + bytes + 255) & ~(size_t)255;
        return ptr;
    };
    u16*   xn1    = (u16*)alloc((size_t)NTOK * HDIM * 2);
    u16*   qb     = (u16*)alloc((size_t)NTOK * 1024 * 2);
    u16*   kb     = (u16*)alloc((size_t)NTOK * 256 * 2);
    u16*   vbt    = (u16*)alloc((size_t)256 * NTOK * 2);
    u16*   ctxb   = (u16*)alloc((size_t)NTOK * 1024 * 2);
    float* hattn  = (float*)alloc((size_t)NTOK * HDIM * 4);
    u16*   xn2    = (u16*)alloc((size_t)NTOK * HDIM * 2);
    float* cosT   = (float*)alloc((size_t)NTOK * 32 * 4);
    float* sinT   = (float*)alloc((size_t)NTOK * 32 * 4);
    int*   counts = (int*)alloc(NE * 4);
    int*   tokslot= (int*)alloc((size_t)NE * NTOK * 4);
    float* wtb    = (float*)alloc((size_t)NE * NTOK * 4);
    u16*   gbuf   = (u16*)alloc((size_t)NE * NTOK * FDIM * 2);
    float* moeb   = (float*)alloc((size_t)2 * NTOK * HDIM * 4);
    u16*   arena  = (u16*)alloc((size_t)N8TOT * 8 * 2);
    u16*   w1b    = arena + (size_t)B4a * 8;
    u16*   w2b    = arena + (size_t)B5b * 8;
    u16*   w3b    = arena + (size_t)B6c * 8;
    u16*   wob    = arena + (size_t)B3o * 8;

    // attention split-KV partials alias gbuf (free until moe_up)
    float* pacc = (float*)gbuf;                                   // 33.5MB
    float* pl   = pacc + (size_t)16 * NTOK * 4 * 64;              // 0.5MB

    hipMemsetAsync(counts, 0, NE * 4, stream);

    prologue_k<<<2560, 256, 0, stream>>>(wq, wk, wv, wo, arena, cosT, sinT, x, ln1, xn1);
    // fused QKV GEMM: B = arena rows 0..1535 (wq|wk|wv), one launch
    qkv_gemm_k<<<dim3(24, 32), 256, 0, stream>>>(xn1, arena, qb, kb, vbt, cosT, sinT);
    // attention + fused w1|w3 convert (z in {4,5}, nontemporal)
    attn_conv_k<<<dim3(32, 16, 6), 256, 0, stream>>>(qb, kb, vbt, pacc, pl,
                                                     w1, w3, arena + (size_t)B4a * 8);
    attn_combine_k<<<8192, 256, 0, stream>>>(pacc, pl, ctxb);
    // O-projection GEMM (+residual) + fused w2 convert (z == 1, nontemporal)
    o_gemm_conv_k<<<dim3(16, 32, 2), 256, 0, stream>>>(ctxb, wob, hattn, x, w2, w2b);
    rmsnorm2_router_k<<<NTOK, 256, 0, stream>>>(hattn, ln2, gw, xn2, out_logits);
    router_topk_k<<<8, 256, 0, stream>>>(out_logits, counts, tokslot, wtb);
    moe_up_k<<<dim3(16, 32, NE), 256, 0, stream>>>(xn2, w1b, w3b, counts, tokslot, gbuf);
    moe_down_k<<<dim3(16, 32, NE), 256, 0, stream>>>(gbuf, w2b, counts, tokslot, wtb, moeb);
    final_add_k<<<NTOK, 256, 0, stream>>>(hattn, moeb, moeb + (size_t)NTOK * HDIM, out_h);
}

// Round 23
// 338.391 us; speedup vs baseline: 1.0107x; 1.0107x over previous
//
#include <hip/hip_runtime.h>
#include <hip/hip_bf16.h>
#include <cstdint>

typedef unsigned short u16;
typedef __attribute__((ext_vector_type(8))) short bh8;   // 8 bf16 (4 VGPR)
typedef __attribute__((ext_vector_type(4))) short sh4;   // 4 bf16
typedef __attribute__((ext_vector_type(4))) float fx4;

#define NTOK 2048
#define HDIM 1024
#define NE 8
#define FDIM 2048

#define VMCNT(n) asm volatile("s_waitcnt vmcnt(" #n ")" ::: "memory")
#define LGKM0()  asm volatile("s_waitcnt lgkmcnt(0)" ::: "memory")
#define SBAR()   __builtin_amdgcn_s_barrier()
#define SCB()    __builtin_amdgcn_sched_barrier(0)

__device__ __forceinline__ u16 f2bf(float f) {
    __hip_bfloat16 h = __float2bfloat16(f);
    return __builtin_bit_cast(u16, h);
}

// async global->LDS, 16B per lane. LDS dest is wave-uniform base (+lane*16 implicit).
__device__ __forceinline__ void gll16(const void* g, void* l) {
    __builtin_amdgcn_global_load_lds(
        (const __attribute__((address_space(1))) void*)g,
        (__attribute__((address_space(3))) void*)l, 16, 0, 0);
}

// ---------------- arena layout (groups of 8 elements): wq|wk|wv|wo|w1|w2|w3
#define N8_WQ 131072
#define N8_WK 32768
#define N8_WV 32768
#define N8_WO 131072
#define N8_W  2097152
#define B0q 0
#define B1k (B0q + N8_WQ)
#define B2v (B1k + N8_WK)
#define B3o (B2v + N8_WV)
#define B4a (B3o + N8_WO)          // qkvo total = 327680
#define B5b (B4a + N8_W)
#define B6c (B5b + N8_W)
#define N8TOT (B6c + N8_W)
#define N8QKVO B4a
#define N8_W13 (2 * N8_W)

// nontemporal f32x8 -> bf16x8 convert (streaming; avoids L2/L3 pollution)
__device__ __forceinline__ void conv8_nt(const float* __restrict__ src, size_t li,
                                         u16* __restrict__ dst, size_t di) {
    const fx4 a = __builtin_nontemporal_load((const fx4*)&src[li]);
    const fx4 b = __builtin_nontemporal_load((const fx4*)&src[li + 4]);
    bh8 o;
    #pragma unroll
    for (int j = 0; j < 4; ++j) {
        o[j]     = (short)f2bf(a[j]);
        o[j + 4] = (short)f2bf(b[j]);
    }
    __builtin_nontemporal_store(o, (bh8*)&dst[di]);
}

__device__ __forceinline__ void conv8(const float* __restrict__ src, size_t li,
                                      u16* __restrict__ dst, size_t di) {
    const fx4 a = *(const fx4*)&src[li];
    const fx4 b = *(const fx4*)&src[li + 4];
    bh8 o;
    #pragma unroll
    for (int j = 0; j < 4; ++j) {
        o[j]     = (short)f2bf(a[j]);
        o[j + 4] = (short)f2bf(b[j]);
    }
    *(bh8*)&dst[di] = o;
}

// ---------------- fused prologue: qkvo convert + rope table + rmsnorm1
// grid 2560 blocks: [0,256) convert qkvo; [256,512) rope; [512,2560) rmsnorm.
__global__ __launch_bounds__(256)
void prologue_k(const float* __restrict__ wq, const float* __restrict__ wk,
                const float* __restrict__ wv, const float* __restrict__ wo,
                u16* __restrict__ arena,
                float* __restrict__ cosT, float* __restrict__ sinT,
                const float* __restrict__ X, const float* __restrict__ W,
                u16* __restrict__ O) {
    const int bid = blockIdx.x;
    const int tid = threadIdx.x;
    if (bid < 256) {
        int i = bid * 256 + tid;
        const int stride = 256 * 256;
        for (; i < N8QKVO; i += stride) {
            const float* src;
            int base;
            if (i < B1k)      { src = wq; base = B0q; }
            else if (i < B2v) { src = wk; base = B1k; }
            else if (i < B3o) { src = wv; base = B2v; }
            else              { src = wo; base = B3o; }
            conv8(src, (size_t)(i - base) * 8, arena, (size_t)i * 8);
        }
        return;
    }
    if (bid < 512) {
        const int idx = (bid - 256) * 256 + tid;      // 2048*32
        const int t = idx >> 5, i = idx & 31;
        const float freq = powf(10000.0f, -(float)i * (1.0f / 32.0f));
        const float ang = (float)t * freq;
        float s, c;
        sincosf(ang, &s, &c);
        cosT[idx] = c;
        sinT[idx] = s;
        return;
    }
    // rmsnorm 1
    const int t = bid - 512;
    const fx4 v = *(const fx4*)&X[(size_t)t * HDIM + tid * 4];
    float ss = v[0]*v[0] + v[1]*v[1] + v[2]*v[2] + v[3]*v[3];
    #pragma unroll
    for (int o = 1; o < 64; o <<= 1) ss += __shfl_xor(ss, o);
    __shared__ float red[4];
    if ((tid & 63) == 0) red[tid >> 6] = ss;
    __syncthreads();
    const float inv = rsqrtf((red[0] + red[1] + red[2] + red[3]) * (1.0f / HDIM) + 1e-5f);
    const fx4 w = *(const fx4*)&W[tid * 4];
    sh4 o4;
    #pragma unroll
    for (int i = 0; i < 4; ++i) o4[i] = (short)f2bf(v[i] * inv * w[i]);
    *(sh4*)&O[(size_t)t * HDIM + tid * 4] = o4;
}

// -------------------------------------------- rmsnorm 2 + router logits (f32)
__global__ __launch_bounds__(256)
void rmsnorm2_router_k(const float* __restrict__ X, const float* __restrict__ W,
                       const float* __restrict__ GW, u16* __restrict__ O,
                       float* __restrict__ LOGI) {
    const int t = blockIdx.x;
    const int tid = threadIdx.x;
    const fx4 v = *(const fx4*)&X[(size_t)t * HDIM + tid * 4];
    float ss = v[0]*v[0] + v[1]*v[1] + v[2]*v[2] + v[3]*v[3];
    #pragma unroll
    for (int o = 1; o < 64; o <<= 1) ss += __shfl_xor(ss, o);
    __shared__ float red[4];
    if ((tid & 63) == 0) red[tid >> 6] = ss;
    __syncthreads();
    const float inv = rsqrtf((red[0] + red[1] + red[2] + red[3]) * (1.0f / HDIM) + 1e-5f);
    const fx4 w = *(const fx4*)&W[tid * 4];
    fx4 xn;
    #pragma unroll
    for (int i = 0; i < 4; ++i) xn[i] = v[i] * inv * w[i];
    sh4 o4;
    #pragma unroll
    for (int i = 0; i < 4; ++i) o4[i] = (short)f2bf(xn[i]);
    *(sh4*)&O[(size_t)t * HDIM + tid * 4] = o4;

    float part[NE];
    #pragma unroll
    for (int e = 0; e < NE; ++e) {
        const fx4 g = *(const fx4*)&GW[(size_t)e * HDIM + tid * 4];
        part[e] = g[0]*xn[0] + g[1]*xn[1] + g[2]*xn[2] + g[3]*xn[3];
    }
    #pragma unroll
    for (int e = 0; e < NE; ++e)
        #pragma unroll
        for (int o = 1; o < 64; o <<= 1) part[e] += __shfl_xor(part[e], o);
    __shared__ float red8[4][NE];
    if ((tid & 63) == 0) {
        #pragma unroll
        for (int e = 0; e < NE; ++e) red8[tid >> 6][e] = part[e];
    }
    __syncthreads();
    if (tid < NE)
        LOGI[(size_t)t * NE + tid] = red8[0][tid] + red8[1][tid] + red8[2][tid] + red8[3][tid];
}

// ---------------------------------------------------------------- router top2
__global__ __launch_bounds__(256)
void router_topk_k(const float* __restrict__ LOGI, int* __restrict__ counts,
                   int* __restrict__ tokslot, float* __restrict__ wtb) {
    const int t = blockIdx.x * 256 + threadIdx.x;
    float l[NE];
    #pragma unroll
    for (int e = 0; e < NE; ++e) l[e] = LOGI[(size_t)t * NE + e];
    int i0 = 0;
    #pragma unroll
    for (int e = 1; e < NE; ++e) if (l[e] > l[i0]) i0 = e;
    int i1 = (i0 == 0) ? 1 : 0;
    #pragma unroll
    for (int e = 0; e < NE; ++e) if (e != i0 && l[e] > l[i1]) i1 = e;
    float e1 = __expf(l[i1] - l[i0]);
    float w0 = 1.0f / (1.0f + e1);
    float w1 = 1.0f - w0;
    int p0 = atomicAdd(&counts[i0], 1);
    tokslot[i0 * NTOK + p0] = t * 2;
    wtb[i0 * NTOK + p0] = w0;
    int p1 = atomicAdd(&counts[i1], 1);
    tokslot[i1 * NTOK + p1] = t * 2 + 1;
    wtb[i1 * NTOK + p1] = w1;
}

// --------------------------------------------- fused QKV GEMM (one launch)
// B = arena rows 0..1535 (wq|wk|wv stacked, K=1024). 64x64 tile, 4-buf
// 3-lookahead pipeline. n-tile epilogue: [0,16) Q+RoPE -> qb; [16,20) K+RoPE
// -> kb; [20,24) V transposed -> vbt. grid (24, 32).
__global__ __launch_bounds__(256)
void qkv_gemm_k(const u16* __restrict__ A, const u16* __restrict__ Bw,
                u16* __restrict__ Qb, u16* __restrict__ Kb, u16* __restrict__ VTb,
                const float* __restrict__ cosT, const float* __restrict__ sinT) {
    __shared__ u16 As[4][64 * 32];
    __shared__ u16 Bs[4][64 * 32];

    const int tid = threadIdx.x;
    const int lane = tid & 63;
    const int wid = tid >> 6;
    const int lrow = lane & 15, lgrp = lane >> 4;
    const int wm = wid * 16;
    const int soff = (lgrp ^ ((lrow >> 1) & 3)) * 8;

    const int m0 = blockIdx.y * 64;
    const int nt = blockIdx.x;
    const int n0 = nt * 64;                 // global arena row base

    const int gseg = ((tid & 3) ^ ((tid >> 3) & 3)) * 8;
    const u16* apg = A + (size_t)(m0 + (tid >> 2)) * 1024 + gseg;
    const u16* bpg = Bw + (size_t)(n0 + (tid >> 2)) * 1024 + gseg;

    fx4 acc[4];
    #pragma unroll
    for (int i = 0; i < 4; ++i) acc[i] = fx4{0.f, 0.f, 0.f, 0.f};

#define G_STG(BUF, KK) gll16(apg + (KK), &As[BUF][wid * 512]); \
                       gll16(bpg + (KK), &Bs[BUF][wid * 512]);
#define G_CMP(BUF)                                                             \
    {                                                                          \
        const bh8 af = *(const bh8*)&As[BUF][(wm + lrow) * 32 + soff];         \
        _Pragma("unroll")                                                      \
        for (int ni = 0; ni < 4; ++ni) {                                       \
            const bh8 bf = *(const bh8*)&Bs[BUF][(ni * 16 + lrow) * 32 + soff];\
            acc[ni] = __builtin_amdgcn_mfma_f32_16x16x32_bf16(af, bf, acc[ni], 0, 0, 0); \
        }                                                                      \
    }
#define G_PHASE(BUF_ST, KOFF, BUF_CM)                                          \
    { const int kn = (k0 + (KOFF) < 1024) ? k0 + (KOFF) : 0; G_STG(BUF_ST, kn) } \
    VMCNT(6); SBAR(); SCB();                                                   \
    G_CMP(BUF_CM)                                                              \
    LGKM0(); SBAR();

    G_STG(0, 0) G_STG(1, 32) G_STG(2, 64)
    for (int k0 = 0; k0 < 1024; k0 += 128) {
        G_PHASE(3, 96, 0)
        G_PHASE(0, 128, 1)
        G_PHASE(1, 160, 2)
        G_PHASE(2, 192, 3)
    }
    VMCNT(0);
#undef G_STG
#undef G_CMP
#undef G_PHASE

    if (nt < 20) {
        // Q (nt<16) or K (16<=nt<20): RoPE epilogue; each 64-col tile = one head
        u16* dst = (nt < 16) ? Qb : Kb;
        const int N = (nt < 16) ? 1024 : 256;
        const int cb = (nt < 16) ? n0 : (nt - 16) * 64;
        #pragma unroll
        for (int j = 0; j < 4; ++j) {
            const int r = m0 + wm + lgrp * 4 + j;
            #pragma unroll
            for (int ni = 0; ni < 2; ++ni) {
                const int d = ni * 16 + lrow;            // d < 32
                const float cv = cosT[r * 32 + d];
                const float sv = sinT[r * 32 + d];
                const float v0 = acc[ni][j];
                const float v1 = acc[ni + 2][j];
                dst[(size_t)r * N + cb + d]      = f2bf(v0 * cv - v1 * sv);
                dst[(size_t)r * N + cb + d + 32] = f2bf(v1 * cv + v0 * sv);
            }
        }
    } else {
        // V: transposed bf16 write; VTb is [256][NTOK]
        #pragma unroll
        for (int ni = 0; ni < 4; ++ni) {
            const int c = (nt - 20) * 64 + ni * 16 + lrow;
            const int r = m0 + wm + lgrp * 4;
            sh4 o4;
            #pragma unroll
            for (int j = 0; j < 4; ++j) o4[j] = (short)f2bf(acc[ni][j]);
            *(sh4*)&VTb[(size_t)c * NTOK + r] = o4;
        }
    }
}

// ------------------------------------------------------------- generic GEMM
// 64x64 tile, 4-buf 3-lookahead. EPI: 1 = f32 + residual(aux0).
template<int EPI>
__global__ __launch_bounds__(256)
void gemm_bt(const u16* __restrict__ A, const u16* __restrict__ B,
             u16* __restrict__ Cb, float* __restrict__ Cf,
             const int N, const int K,
             const float* __restrict__ aux0, const float* __restrict__ aux1) {
    __shared__ u16 As[4][64 * 32];
    __shared__ u16 Bs[4][64 * 32];

    const int tid = threadIdx.x;
    const int lane = tid & 63;
    const int wid = tid >> 6;
    const int lrow = lane & 15, lgrp = lane >> 4;
    const int wm = wid * 16;
    const int soff = (lgrp ^ ((lrow >> 1) & 3)) * 8;

    const int m0 = blockIdx.y * 64;
    const int n0 = blockIdx.x * 64;

    const int gseg = ((tid & 3) ^ ((tid >> 3) & 3)) * 8;
    const u16* apg = A + (size_t)(m0 + (tid >> 2)) * K + gseg;
    const u16* bpg = B + (size_t)(n0 + (tid >> 2)) * K + gseg;

    fx4 acc[4];
    #pragma unroll
    for (int i = 0; i < 4; ++i) acc[i] = fx4{0.f, 0.f, 0.f, 0.f};

#define G_STG(BUF, KK) gll16(apg + (KK), &As[BUF][wid * 512]); \
                       gll16(bpg + (KK), &Bs[BUF][wid * 512]);
#define G_CMP(BUF)                                                             \
    {                                                                          \
        const bh8 af = *(const bh8*)&As[BUF][(wm + lrow) * 32 + soff];         \
        _Pragma("unroll")                                                      \
        for (int ni = 0; ni < 4; ++ni) {                                       \
            const bh8 bf = *(const bh8*)&Bs[BUF][(ni * 16 + lrow) * 32 + soff];\
            acc[ni] = __builtin_amdgcn_mfma_f32_16x16x32_bf16(af, bf, acc[ni], 0, 0, 0); \
        }                                                                      \
    }
#define G_PHASE(BUF_ST, KOFF, BUF_CM)                                          \
    { const int kn = (k0 + (KOFF) < K) ? k0 + (KOFF) : 0; G_STG(BUF_ST, kn) }  \
    VMCNT(6); SBAR(); SCB();                                                   \
    G_CMP(BUF_CM)                                                              \
    LGKM0(); SBAR();

    G_STG(0, 0) G_STG(1, 32) G_STG(2, 64)
    for (int k0 = 0; k0 < K; k0 += 128) {
        G_PHASE(3, 96, 0)
        G_PHASE(0, 128, 1)
        G_PHASE(1, 160, 2)
        G_PHASE(2, 192, 3)
    }
    VMCNT(0);
#undef G_STG
#undef G_CMP
#undef G_PHASE

    #pragma unroll
    for (int j = 0; j < 4; ++j) {
        const int r = m0 + wm + lgrp * 4 + j;
        #pragma unroll
        for (int ni = 0; ni < 4; ++ni) {
            const int c = n0 + ni * 16 + lrow;
            const float v = acc[ni][j];
            if (EPI == 1) Cf[(size_t)r * N + c] = v + aux0[(size_t)r * N + c];
        }
    }
}

// --------------------------- flash attention (split-KV) + fused w1|w3 convert
// z in [0,4): attention chunks (fixed-max softmax, shift-exact; V pre-
// transposed). z in {4,5}: 1024 grid-stride blocks convert w1|w3 (NT, 4x MLP).
__global__ __launch_bounds__(256)
void attn_conv_k(const u16* __restrict__ Q, const u16* __restrict__ Kg,
                 const u16* __restrict__ VTg, float* __restrict__ pacc,
                 float* __restrict__ pl,
                 const float* __restrict__ w1, const float* __restrict__ w3,
                 u16* __restrict__ arena_moe) {
    if (blockIdx.z >= 4) {
        const int bid = (blockIdx.z - 4) * 512 + blockIdx.y * 32 + blockIdx.x; // 0..1023
        const int stride = 1024 * 256;
        int i = bid * 256 + threadIdx.x;
        // N8_W13 / stride = 16 iterations; unroll 4 for MLP
        #pragma unroll 1
        for (int k = 0; k < 4; ++k) {
            #pragma unroll
            for (int u = 0; u < 4; ++u) {
                const int ii = i + u * stride;
                const float* s = (ii < N8_W) ? w1 : w3;
                const size_t li = (size_t)(ii < N8_W ? ii : ii - N8_W) * 8;
                const size_t di = (size_t)(ii < N8_W ? ii : ii + N8_W) * 8;  // w3 -> rel 2*N8_W
                conv8_nt(s, li, arena_moe, di);
            }
            i += 4 * stride;
        }
        return;
    }

    const int qt = blockIdx.x;
    const int h = blockIdx.y;
    const int c = blockIdx.z;
    if (c * 8 > qt) return;
    const int t0 = c * 8;
    const int tend = min(qt + 1, t0 + 8);
    const int kvh = h >> 2;

    const int tid = threadIdx.x;
    const int lane = tid & 63;
    const int wid = tid >> 6;
    const int lrow = lane & 15, lgrp = lane >> 4;

    __shared__ u16 Ks[64 * 66];
    __shared__ u16 Vs[64 * 66];
    __shared__ u16 Ps[4][16 * 66];

    const int qbase = qt * 64 + wid * 16;

    bh8 qf[2];
    #pragma unroll
    for (int kf = 0; kf < 2; ++kf)
        qf[kf] = *(const bh8*)&Q[(size_t)(qbase + lrow) * 1024 + h * 64 + kf * 32 + lgrp * 8];

    fx4 acc[4];
    #pragma unroll
    for (int ni = 0; ni < 4; ++ni) acc[ni] = fx4{0.f, 0.f, 0.f, 0.f};
    float lsum[4];
    #pragma unroll
    for (int j = 0; j < 4; ++j) lsum[j] = 0.f;

    const int srow = tid >> 2;
    const int sseg = (tid & 3) * 16;

    size_t gk = (size_t)(t0 * 64 + srow) * 256 + kvh * 64 + sseg;
    size_t gv = (size_t)(kvh * 64 + srow) * NTOK + t0 * 64 + sseg;
    bh8 kva = *(const bh8*)&Kg[gk];
    bh8 kvb = *(const bh8*)&Kg[gk + 8];
    bh8 vva = *(const bh8*)&VTg[gv];
    bh8 vvb = *(const bh8*)&VTg[gv + 8];

    for (int it = t0; it < tend; ++it) {
        const int kv0 = it * 64;
        __syncthreads();
        *(bh8*)&Ks[srow * 66 + sseg]     = kva;
        *(bh8*)&Ks[srow * 66 + sseg + 8] = kvb;
        *(bh8*)&Vs[srow * 66 + sseg]     = vva;
        *(bh8*)&Vs[srow * 66 + sseg + 8] = vvb;
        __syncthreads();

        const int itn = (it + 1 < tend) ? it + 1 : it;
        const size_t gk2 = (size_t)(itn * 64 + srow) * 256 + kvh * 64 + sseg;
        const size_t gv2 = (size_t)(kvh * 64 + srow) * NTOK + itn * 64 + sseg;
        kva = *(const bh8*)&Kg[gk2];
        kvb = *(const bh8*)&Kg[gk2 + 8];
        vva = *(const bh8*)&VTg[gv2];
        vvb = *(const bh8*)&VTg[gv2 + 8];

        fx4 s[4];
        #pragma unroll
        for (int nf = 0; nf < 4; ++nf) s[nf] = fx4{0.f, 0.f, 0.f, 0.f};
        #pragma unroll
        for (int kf = 0; kf < 2; ++kf) {
            #pragma unroll
            for (int nf = 0; nf < 4; ++nf) {
                const bh8 kfr = *(const bh8*)&Ks[(nf * 16 + lrow) * 66 + kf * 32 + lgrp * 8];
                s[nf] = __builtin_amdgcn_mfma_f32_16x16x32_bf16(qf[kf], kfr, s[nf], 0, 0, 0);
            }
        }

        #pragma unroll
        for (int nf = 0; nf < 4; ++nf)
            #pragma unroll
            for (int j = 0; j < 4; ++j) {
                const int qr = qbase + lgrp * 4 + j;
                const int kp = kv0 + nf * 16 + lrow;
                float p = __expf(fmaf(s[nf][j], 0.125f, -24.0f));
                p = (kp > qr) ? 0.f : p;
                s[nf][j] = p;
                lsum[j] += p;
            }

        u16* pw = Ps[wid];
        #pragma unroll
        for (int nf = 0; nf < 4; ++nf)
            #pragma unroll
            for (int j = 0; j < 4; ++j)
                pw[(lgrp * 4 + j) * 66 + nf * 16 + lrow] = f2bf(s[nf][j]);

        #pragma unroll
        for (int kf = 0; kf < 2; ++kf) {
            const bh8 pa = *(const bh8*)&pw[lrow * 66 + kf * 32 + lgrp * 8];
            #pragma unroll
            for (int ni = 0; ni < 4; ++ni) {
                const bh8 vb = *(const bh8*)&Vs[(ni * 16 + lrow) * 66 + kf * 32 + lgrp * 8];
                acc[ni] = __builtin_amdgcn_mfma_f32_16x16x32_bf16(pa, vb, acc[ni], 0, 0, 0);
            }
        }
    }

    #pragma unroll
    for (int j = 0; j < 4; ++j) {
        float l = lsum[j];
        #pragma unroll
        for (int o = 1; o < 16; o <<= 1) l += __shfl_xor(l, o);
        lsum[j] = l;
    }

    #pragma unroll
    for (int j = 0; j < 4; ++j) {
        const int r = qbase + lgrp * 4 + j;
        const size_t base = ((size_t)(h * NTOK + r) * 4 + c) * 64;
        #pragma unroll
        for (int ni = 0; ni < 4; ++ni)
            pacc[base + ni * 16 + lrow] = acc[ni][j];
        if (lrow == 0)
            pl[(size_t)(h * NTOK + r) * 4 + c] = lsum[j];
    }
}

// --------------------------------------------- attention combine (plain sums)
__global__ __launch_bounds__(256)
void attn_combine_k(const float* __restrict__ pacc, const float* __restrict__ pl,
                    u16* __restrict__ O) {
    const int idx = blockIdx.x * 4 + (threadIdx.x >> 6);
    const int d = threadIdx.x & 63;
    const int h = idx >> 11;
    const int qrow = idx & 2047;
    const int nch = (qrow >> 9) + 1;

    float den = 0.f, num = 0.f;
    for (int c = 0; c < nch; ++c) {
        den += pl[(size_t)idx * 4 + c];
        num += pacc[((size_t)idx * 4 + c) * 64 + d];
    }
    O[(size_t)qrow * 1024 + h * 64 + d] = f2bf(num / den);
}

// ------------------------------- MoE up (w1,w3 + SiLU*mul) + fused w2 convert
// z in [0,8): 64x128 tile, 4 waves (2x2). 4-buffer 3-phase-lookahead:
// stage(t+3), vmcnt(15), compute(t). 80KB LDS.
// z == 8: 512 grid-stride blocks convert w2 (NT, 4x MLP); ready before moe_down.
__global__ __launch_bounds__(256)
void moe_up_k(const u16* __restrict__ X, const u16* __restrict__ W1b,
              const u16* __restrict__ W3b, const int* __restrict__ counts,
              const int* __restrict__ tokslot, u16* __restrict__ G,
              const float* __restrict__ w2, u16* __restrict__ w2b) {
    if (blockIdx.z == 8) {
        const int bid = blockIdx.y * 16 + blockIdx.x;      // 0..511
        const int stride = 512 * 256;
        int i = bid * 256 + threadIdx.x;
        // N8_W / stride = 16 iterations; unroll 4
        #pragma unroll 1
        for (int k = 0; k < 4; ++k) {
            #pragma unroll
            for (int u = 0; u < 4; ++u)
                conv8_nt(w2, (size_t)(i + u * stride) * 8, w2b, (size_t)(i + u * stride) * 8);
            i += 4 * stride;
        }
        return;
    }

    const int e = blockIdx.z;
    const int cnt = counts[e];
    const int m0 = blockIdx.y * 64;
    if (m0 >= cnt) return;
    const int n0 = blockIdx.x * 128;

    __shared__ u16 As[4][64 * 32];
    __shared__ u16 B1s[4][128 * 32];
    __shared__ u16 B3s[4][128 * 32];

    const int tid = threadIdx.x;
    const int lane = tid & 63, wid = tid >> 6;
    const int wm = (wid >> 1) * 32, wn = (wid & 1) * 64;
    const int lrow = lane & 15, lgrp = lane >> 4;
    const int soff = (lgrp ^ ((lrow >> 1) & 3)) * 8;

    const int gseg = ((tid & 3) ^ ((tid >> 3) & 3)) * 8;
    const int arow = m0 + (tid >> 2);
    const int tok = (arow < cnt) ? (tokslot[e * NTOK + arow] >> 1) : 0;
    const u16* apg = X + (size_t)tok * HDIM + gseg;
    const size_t eoff = (size_t)e * FDIM * HDIM;
    const u16* b1pg = W1b + eoff + (size_t)(n0 + (tid >> 2)) * HDIM + gseg;
    const u16* b3pg = W3b + eoff + (size_t)(n0 + (tid >> 2)) * HDIM + gseg;
    const size_t rr = (size_t)64 * HDIM;

    fx4 acc1[2][4], acc3[2][4];
    #pragma unroll
    for (int i = 0; i < 2; ++i)
        #pragma unroll
        for (int j = 0; j < 4; ++j) {
            acc1[i][j] = fx4{0.f, 0.f, 0.f, 0.f};
            acc3[i][j] = fx4{0.f, 0.f, 0.f, 0.f};
        }

#define U_STG(BUF, KK)                                          \
    gll16(apg + (KK), &As[BUF][wid * 512]);                     \
    gll16(b1pg + (KK), &B1s[BUF][wid * 512]);                   \
    gll16(b1pg + rr + (KK), &B1s[BUF][2048 + wid * 512]);       \
    gll16(b3pg + (KK), &B3s[BUF][wid * 512]);                   \
    gll16(b3pg + rr + (KK), &B3s[BUF][2048 + wid * 512]);

#define U_CMP(BUF)                                                                   \
    {                                                                                \
        bh8 af[2], b1f[4], b3f[4];                                                   \
        _Pragma("unroll")                                                            \
        for (int mi = 0; mi < 2; ++mi)                                               \
            af[mi] = *(const bh8*)&As[BUF][(wm + mi * 16 + lrow) * 32 + soff];       \
        _Pragma("unroll")                                                            \
        for (int ni = 0; ni < 4; ++ni) {                                             \
            b1f[ni] = *(const bh8*)&B1s[BUF][(wn + ni * 16 + lrow) * 32 + soff];     \
            b3f[ni] = *(const bh8*)&B3s[BUF][(wn + ni * 16 + lrow) * 32 + soff];     \
        }                                                                            \
        _Pragma("unroll")                                                            \
        for (int mi = 0; mi < 2; ++mi)                                               \
            _Pragma("unroll")                                                        \
            for (int ni = 0; ni < 4; ++ni) {                                         \
                acc1[mi][ni] = __builtin_amdgcn_mfma_f32_16x16x32_bf16(af[mi], b1f[ni], acc1[mi][ni], 0, 0, 0); \
                acc3[mi][ni] = __builtin_amdgcn_mfma_f32_16x16x32_bf16(af[mi], b3f[ni], acc3[mi][ni], 0, 0, 0); \
            }                                                                        \
    }

#define U_PHASE(BUF_ST, KOFF, BUF_CM)                                          \
    { const int kn = (k0 + (KOFF) < HDIM) ? k0 + (KOFF) : 0; U_STG(BUF_ST, kn) } \
    VMCNT(15); SBAR(); SCB();                                                  \
    U_CMP(BUF_CM)                                                              \
    LGKM0(); SBAR();

    U_STG(0, 0) U_STG(1, 32) U_STG(2, 64)
    for (int k0 = 0; k0 < HDIM; k0 += 128) {
        U_PHASE(3, 96, 0)
        U_PHASE(0, 128, 1)
        U_PHASE(1, 160, 2)
        U_PHASE(2, 192, 3)
    }
    VMCNT(0);
#undef U_STG
#undef U_CMP
#undef U_PHASE

    #pragma unroll
    for (int mi = 0; mi < 2; ++mi)
        #pragma unroll
        for (int j = 0; j < 4; ++j) {
            const int r = m0 + wm + mi * 16 + lgrp * 4 + j;
            if (r < cnt) {
                #pragma unroll
                for (int ni = 0; ni < 4; ++ni) {
                    const int c = n0 + wn + ni * 16 + lrow;
                    const float h1 = acc1[mi][ni][j];
                    const float h3 = acc3[mi][ni][j];
                    const float gv = h1 / (1.0f + __expf(-h1)) * h3;
                    G[((size_t)e * NTOK + r) * FDIM + c] = f2bf(gv);
                }
            }
        }
}

// -------------------------------------------------- MoE down (scaled scatter)
// 64x64 tile, K=2048, 4-buf 3-lookahead pipeline, scatter epilogue.
__global__ __launch_bounds__(256)
void moe_down_k(const u16* __restrict__ G, const u16* __restrict__ W2b,
                const int* __restrict__ counts, const int* __restrict__ tokslot,
                const float* __restrict__ wtb, float* __restrict__ MO) {
    const int e = blockIdx.z;
    const int cnt = counts[e];
    const int m0 = blockIdx.y * 64;
    if (m0 >= cnt) return;
    const int n0 = blockIdx.x * 64;

    __shared__ u16 As[4][64 * 32];
    __shared__ u16 Bs[4][64 * 32];

    const int tid = threadIdx.x;
    const int lane = tid & 63;
    const int wid = tid >> 6;
    const int lrow = lane & 15, lgrp = lane >> 4;
    const int wm = wid * 16;
    const int soff = (lgrp ^ ((lrow >> 1) & 3)) * 8;

    const int gseg = ((tid & 3) ^ ((tid >> 3) & 3)) * 8;
    const u16* apg = G + ((size_t)e * NTOK + m0 + (tid >> 2)) * FDIM + gseg;
    const u16* bpg = W2b + (size_t)e * HDIM * FDIM + (size_t)(n0 + (tid >> 2)) * FDIM + gseg;

    fx4 acc[4];
    #pragma unroll
    for (int i = 0; i < 4; ++i) acc[i] = fx4{0.f, 0.f, 0.f, 0.f};

#define D_STG(BUF, KK) gll16(apg + (KK), &As[BUF][wid * 512]); \
                       gll16(bpg + (KK), &Bs[BUF][wid * 512]);
#define D_CMP(BUF)                                                             \
    {                                                                          \
        const bh8 af = *(const bh8*)&As[BUF][(wm + lrow) * 32 + soff];         \
        _Pragma("unroll")                                                      \
        for (int ni = 0; ni < 4; ++ni) {                                       \
            const bh8 bf = *(const bh8*)&Bs[BUF][(ni * 16 + lrow) * 32 + soff];\
            acc[ni] = __builtin_amdgcn_mfma_f32_16x16x32_bf16(af, bf, acc[ni], 0, 0, 0); \
        }                                                                      \
    }
#define D_PHASE(BUF_ST, KOFF, BUF_CM)                                          \
    { const int kn = (k0 + (KOFF) < FDIM) ? k0 + (KOFF) : 0; D_STG(BUF_ST, kn) } \
    VMCNT(6); SBAR(); SCB();                                                   \
    D_CMP(BUF_CM)                                                              \
    LGKM0(); SBAR();

    D_STG(0, 0) D_STG(1, 32) D_STG(2, 64)
    for (int k0 = 0; k0 < FDIM; k0 += 128) {
        D_PHASE(3, 96, 0)
        D_PHASE(0, 128, 1)
        D_PHASE(1, 160, 2)
        D_PHASE(2, 192, 3)
    }
    VMCNT(0);
#undef D_STG
#undef D_CMP
#undef D_PHASE

    #pragma unroll
    for (int j = 0; j < 4; ++j) {
        const int r = m0 + wm + lgrp * 4 + j;
        if (r < cnt) {
            const int ts = tokslot[e * NTOK + r];
            const float wgt = wtb[e * NTOK + r];
            const int tt = ts >> 1;
            const int sl = ts & 1;
            #pragma unroll
            for (int ni = 0; ni < 4; ++ni) {
                const int c = n0 + ni * 16 + lrow;
                MO[((size_t)sl * NTOK + tt) * HDIM + c] = acc[ni][j] * wgt;
            }
        }
    }
}

// ---------------------------------------------------------------- final add
__global__ __launch_bounds__(256)
void final_add_k(const float* __restrict__ A, const float* __restrict__ B0,
                 const float* __restrict__ B1, float* __restrict__ O) {
    const size_t i = ((size_t)blockIdx.x * 256 + threadIdx.x) * 4;
    const fx4 a = *(const fx4*)&A[i];
    const fx4 b = *(const fx4*)&B0[i];
    const fx4 c = *(const fx4*)&B1[i];
    fx4 r;
    #pragma unroll
    for (int k = 0; k < 4; ++k) r[k] = a[k] + b[k] + c[k];
    *(fx4*)&O[i] = r;
}

// ---------------------------------------------------------------- launcher
extern "C" void kernel_launch(void* const* d_in, const int* in_sizes, int n_in,
                              void* d_out, int out_size, void* d_ws, size_t ws_size,
                              hipStream_t stream) {
    const float* x   = (const float*)d_in[0];
    const float* ln1 = (const float*)d_in[2];
    const float* ln2 = (const float*)d_in[3];
    const float* wq  = (const float*)d_in[4];
    const float* wk  = (const float*)d_in[5];
    const float* wv  = (const float*)d_in[6];
    const float* wo  = (const float*)d_in[7];
    const float* gw  = (const float*)d_in[8];
    const float* w1  = (const float*)d_in[9];
    const float* w2  = (const float*)d_in[10];
    const float* w3  = (const float*)d_in[11];

    float* out_h = (float*)d_out;
    float* out_logits = out_h + (size_t)NTOK * HDIM;

    uint8_t* wsb = (uint8_t*)d_ws;
    size_t off = 0;
    auto alloc = [&](size_t bytes) -> void* {
        void* ptr = wsb + off;
        off = (off + bytes + 255) & ~(size_t)255;
        return ptr;
    };
    u16*   xn1    = (u16*)alloc((size_t)NTOK * HDIM * 2);
    u16*   qb     = (u16*)alloc((size_t)NTOK * 1024 * 2);
    u16*   kb     = (u16*)alloc((size_t)NTOK * 256 * 2);
    u16*   vbt    = (u16*)alloc((size_t)256 * NTOK * 2);
    u16*   ctxb   = (u16*)alloc((size_t)NTOK * 1024 * 2);
    float* hattn  = (float*)alloc((size_t)NTOK * HDIM * 4);
    u16*   xn2    = (u16*)alloc((size_t)NTOK * HDIM * 2);
    float* cosT   = (float*)alloc((size_t)NTOK * 32 * 4);
    float* sinT   = (float*)alloc((size_t)NTOK * 32 * 4);
    int*   counts = (int*)alloc(NE * 4);
    int*   tokslot= (int*)alloc((size_t)NE * NTOK * 4);
    float* wtb    = (float*)alloc((size_t)NE * NTOK * 4);
    u16*   gbuf   = (u16*)alloc((size_t)NE * NTOK * FDIM * 2);
    float* moeb   = (float*)alloc((size_t)2 * NTOK * HDIM * 4);
    u16*   arena  = (u16*)alloc((size_t)N8TOT * 8 * 2);
    u16*   w1b    = arena + (size_t)B4a * 8;
    u16*   w2b    = arena + (size_t)B5b * 8;
    u16*   w3b    = arena + (size_t)B6c * 8;
    u16*   wob    = arena + (size_t)B3o * 8;

    // attention split-KV partials alias gbuf (free until moe_up)
    float* pacc = (float*)gbuf;                                   // 33.5MB
    float* pl   = pacc + (size_t)16 * NTOK * 4 * 64;              // 0.5MB

    hipMemsetAsync(counts, 0, NE * 4, stream);

    prologue_k<<<2560, 256, 0, stream>>>(wq, wk, wv, wo, arena, cosT, sinT, x, ln1, xn1);
    // fused QKV GEMM: B = arena rows 0..1535 (wq|wk|wv), one launch
    qkv_gemm_k<<<dim3(24, 32), 256, 0, stream>>>(xn1, arena, qb, kb, vbt, cosT, sinT);
    // attention + fused w1|w3 convert (z in {4,5}, nontemporal)
    attn_conv_k<<<dim3(32, 16, 6), 256, 0, stream>>>(qb, kb, vbt, pacc, pl,
                                                     w1, w3, arena + (size_t)B4a * 8);
    attn_combine_k<<<8192, 256, 0, stream>>>(pacc, pl, ctxb);
    gemm_bt<1><<<dim3(16, 32), 256, 0, stream>>>(ctxb, wob, nullptr, hattn, 1024, 1024, x, nullptr);
    rmsnorm2_router_k<<<NTOK, 256, 0, stream>>>(hattn, ln2, gw, xn2, out_logits);
    router_topk_k<<<8, 256, 0, stream>>>(out_logits, counts, tokslot, wtb);
    // moe_up + fused w2 convert (z == 8, nontemporal); w2b ready before moe_down
    moe_up_k<<<dim3(16, 32, NE + 1), 256, 0, stream>>>(xn2, w1b, w3b, counts, tokslot, gbuf,
                                                       w2, w2b);
    moe_down_k<<<dim3(16, 32, NE), 256, 0, stream>>>(gbuf, w2b, counts, tokslot, wtb, moeb);
    final_add_k<<<NTOK, 256, 0, stream>>>(hattn, moeb, moeb + (size_t)NTOK * HDIM, out_h);
}